// Round 8
// baseline (734.684 us; speedup 1.0000x reference)
//
#include <hip/hip_runtime.h>

#define NPTS  32768
#define DIM   256
#define KCB   1024
#define CL    24

#define ZQ_OFF   0
#define LOSS_OFF 8388608
#define IDX_OFF  8388609

typedef __attribute__((ext_vector_type(8))) short short8;
typedef __attribute__((ext_vector_type(4))) float f32x4;

// z layout [B, D, H, W]: point n = b*1024 + h*32 + w ; elem (n,d) at b*262144 + d*1024 + hw
__device__ __forceinline__ int z_base(int n) { return ((n >> 10) << 18) | (n & 1023); }

// RNE float->bf16 (bits)
__device__ __forceinline__ unsigned short f2bf(float f) {
    unsigned u = __float_as_uint(f);
    u += 0x7FFFu + ((u >> 16) & 1u);
    return (unsigned short)(u >> 16);
}

__device__ __forceinline__ unsigned long long pack_vi(float v, int i) {
    unsigned int u = __float_as_uint(v);
    unsigned int key = (u & 0x80000000u) ? ~u : u;   // monotone float->uint (finite)
    return ((unsigned long long)key << 32) | (unsigned int)i;
}

// ---- numpy pairwise sum (AVX512 npyv order) of squares, 128 elems, stride 1 ----
__device__ __forceinline__ float np_half_sq(const float* __restrict__ p) {
    float S[16];
#pragma unroll
    for (int l = 0; l < 16; ++l) {
        float t[8];
#pragma unroll
        for (int j = 0; j < 8; ++j) {
            float v = p[j * 16 + l];
            t[j] = __fmul_rn(v, v);
        }
        S[l] = __fadd_rn(__fadd_rn(__fadd_rn(t[0], t[1]), __fadd_rn(t[2], t[3])),
                         __fadd_rn(__fadd_rn(t[4], t[5]), __fadd_rn(t[6], t[7])));
    }
    float u[8];
#pragma unroll
    for (int i = 0; i < 8; ++i) u[i] = __fadd_rn(S[i], S[i + 8]);
    float v4[4];
#pragma unroll
    for (int i = 0; i < 4; ++i) v4[i] = __fadd_rn(u[i], u[i + 4]);
    return __fadd_rn(__fadd_rn(v4[0], v4[2]), __fadd_rn(v4[1], v4[3]));
}

// emb-side setup only: 4 blocks. bf16 convert + e2/e2h + zero accumulators.
__global__ __launch_bounds__(256) void setup_e_kernel(
    const float* __restrict__ emb, float* __restrict__ e2, float* __restrict__ e2h,
    unsigned short* __restrict__ ebf,
    double* __restrict__ loss_acc, unsigned int* __restrict__ ticket)
{
    const int tid = threadIdx.x;
    const int kb = blockIdx.x << 8;
    const float2* s2 = (const float2*)(emb + (kb << 8));
    unsigned int* d2 = (unsigned int*)(ebf + (kb << 8));
    for (int i = tid; i < 256 * 128; i += 256) {
        float2 v = s2[i];
        d2[i] = (unsigned)f2bf(v.x) | ((unsigned)f2bf(v.y) << 16);
    }
    int k = kb + tid;
    float s = __fadd_rn(np_half_sq(emb + (k << 8)), np_half_sq(emb + (k << 8) + 128));
    e2[k] = s;
    e2h[k] = 0.5f * s;
    if (blockIdx.x == 0 && tid == 0) { *loss_acc = 0.0; *ticket = 0u; }
}

// ============ fused: z2/eps + MFMA filter + exact recheck + idx/zq/loss ============
// block = 64 points, 4 waves; wave owns all 64 pts x its 256-k quarter (barrier-free filter).
#define ZS_STRIDE 264

__global__ __launch_bounds__(256) void vq_kernel(
    const float* __restrict__ z, const float* __restrict__ emb,
    const unsigned short* __restrict__ ebf,
    const float* __restrict__ e2w, const float* __restrict__ e2hw,
    float* __restrict__ out_idx, float* __restrict__ zq,
    double* __restrict__ loss_acc, unsigned int* __restrict__ ticket,
    float* __restrict__ out_loss)
{
    __shared__ __align__(16) short zs[64 * ZS_STRIDE];   // bf16 A tile (33792 B)
    __shared__ __align__(16) float zx[32 * 68];          // fp32 chunk (8704 B), reused all phases
    __shared__ __align__(16) int clS[64 * CL];           // cand lists; aliased in phase 0
    __shared__ unsigned int cntS[64];
    __shared__ unsigned long long bestS[64];
    __shared__ float z2S[64], epsS[64];
    __shared__ int offS[65];
    __shared__ int kbS[64];
    __shared__ double sredL[4];
    __shared__ int ovfS;

    const int tid = threadIdx.x;
    const int w   = tid >> 6;
    const int l   = tid & 63;
    const int n16 = l & 15;
    const int q   = l >> 4;
    const int n0  = blockIdx.x << 6;
    const int zb  = z_base(n0);
    const int kq  = w << 8;

    // phase-0 scratch aliased over clS (clS used only from the filter onward)
    float* Sbuf = (float*)clS;               // [64 pt][16 l]
    float* Abuf = Sbuf + 1024;               // [4 c][64 pt]
    float* z2h  = Abuf + 256;                // [64 pt]

    if (tid < 64) { cntS[tid] = 0u; bestS[tid] = 0x7FFFFFFFFFFFFFFFULL; }
    if (tid == 0) ovfS = 0;

    // -------- phase 0: stage z (fp32->zx, bf16->zs) + exact np z2 + eps --------
    const int qq  = tid & 15;                // staging: point quad
    const int dd0 = tid >> 4;                // staging: d row 0..15
    const int cc  = tid >> 6;                // compute: l-group 4cc..4cc+3
    const int pt0 = tid & 63;                // compute: point
    float pend[4], l2a[4];
    float asum = 0.0f;

#pragma unroll 1
    for (int dc = 0; dc < 8; ++dc) {
        {
            const float* zc = z + zb + (((dc << 5) + dd0) << 10) + 4 * qq;
            float4 v0 = *(const float4*)zc;
            float4 v1 = *(const float4*)(zc + (16 << 10));
            *(float4*)(zx + dd0 * 68 + 4 * qq) = v0;
            *(float4*)(zx + (dd0 + 16) * 68 + 4 * qq) = v1;
            const int db = (dc << 5) + dd0;
            zs[(4 * qq + 0) * ZS_STRIDE + db] = (short)f2bf(v0.x);
            zs[(4 * qq + 1) * ZS_STRIDE + db] = (short)f2bf(v0.y);
            zs[(4 * qq + 2) * ZS_STRIDE + db] = (short)f2bf(v0.z);
            zs[(4 * qq + 3) * ZS_STRIDE + db] = (short)f2bf(v0.w);
            zs[(4 * qq + 0) * ZS_STRIDE + db + 16] = (short)f2bf(v1.x);
            zs[(4 * qq + 1) * ZS_STRIDE + db + 16] = (short)f2bf(v1.y);
            zs[(4 * qq + 2) * ZS_STRIDE + db + 16] = (short)f2bf(v1.z);
            zs[(4 * qq + 3) * ZS_STRIDE + db + 16] = (short)f2bf(v1.w);
        }
        __syncthreads();
        // np tree nodes in arrival order: chunk dc gives j = {2dc, 2dc+1} (mod half)
#pragma unroll
        for (int i = 0; i < 4; ++i) {
            int ll = 4 * cc + i;
            float a0 = zx[ll * 68 + pt0];
            float a1 = zx[(16 + ll) * 68 + pt0];
            float t0 = __fmul_rn(a0, a0), t1 = __fmul_rn(a1, a1);
            float p = __fadd_rn(t0, t1);
            asum += fabsf(a0) + fabsf(a1);
            if ((dc & 1) == 0)       pend[i] = p;
            else if ((dc & 3) == 1)  l2a[i] = __fadd_rn(pend[i], p);
            else {                   // dc&3 == 3: S[l] complete for this half
                float S = __fadd_rn(l2a[i], __fadd_rn(pend[i], p));
                Sbuf[pt0 * 16 + ll] = S;
            }
        }
        if (dc == 7) Abuf[cc * 64 + pt0] = asum;
        if (dc == 4 && tid < 64) {   // combine half 0 (Sbuf stable until dc==7)
            float u[8], v4[4];
#pragma unroll
            for (int i = 0; i < 8; ++i) u[i] = __fadd_rn(Sbuf[tid * 16 + i], Sbuf[tid * 16 + i + 8]);
#pragma unroll
            for (int i = 0; i < 4; ++i) v4[i] = __fadd_rn(u[i], u[i + 4]);
            z2h[tid] = __fadd_rn(__fadd_rn(v4[0], v4[2]), __fadd_rn(v4[1], v4[3]));
        }
        __syncthreads();
    }
    if (tid < 64) {                  // combine half 1 -> z2, eps
        float u[8], v4[4];
#pragma unroll
        for (int i = 0; i < 8; ++i) u[i] = __fadd_rn(Sbuf[tid * 16 + i], Sbuf[tid * 16 + i + 8]);
#pragma unroll
        for (int i = 0; i < 4; ++i) v4[i] = __fadd_rn(u[i], u[i + 4]);
        float h1 = __fadd_rn(__fadd_rn(v4[0], v4[2]), __fadd_rn(v4[1], v4[3]));
        z2S[tid] = __fadd_rn(z2h[tid], h1);
        float A = ((Abuf[tid] + Abuf[64 + tid]) + (Abuf[128 + tid] + Abuf[192 + tid]));
        epsS[tid] = __builtin_fmaf(1e-5f, A, 3e-4f);  // sound |s~-s| two-sided bound
    }
    __syncthreads();

    // -------- phase 1: barrier-free MFMA filter (2-deep B prefetch) --------
    f32x4 acc[4][4];
    float Mx[4][4];
#pragma unroll
    for (int mt = 0; mt < 4; ++mt)
#pragma unroll
        for (int nt = 0; nt < 4; ++nt) acc[mt][nt] = (f32x4)0.0f;
#pragma unroll
    for (int mt = 0; mt < 4; ++mt)
#pragma unroll
        for (int r = 0; r < 4; ++r) Mx[mt][r] = -3.4e38f;

    int4 bbuf[2][4];
#pragma unroll
    for (int nt = 0; nt < 4; ++nt)
        bbuf[0][nt] = *(const int4*)(ebf + ((kq + nt * 16 + n16) << 8) + q * 8);
#pragma unroll
    for (int nt = 0; nt < 4; ++nt)
        bbuf[1][nt] = *(const int4*)(ebf + ((kq + nt * 16 + n16) << 8) + 32 + q * 8);

#pragma unroll 1
    for (int step = 0; step < 32; ++step) {
        const int s = step >> 3, dc = step & 7, cur = step & 1;
        short8 af[4];
#pragma unroll
        for (int mt = 0; mt < 4; ++mt)
            af[mt] = *(const short8*)(zs + (mt * 16 + n16) * ZS_STRIDE + dc * 32 + q * 8);
#pragma unroll
        for (int nt = 0; nt < 4; ++nt) {
            short8 bf = *(short8*)&bbuf[cur][nt];
#pragma unroll
            for (int mt = 0; mt < 4; ++mt)
                acc[mt][nt] = __builtin_amdgcn_mfma_f32_16x16x32_bf16(af[mt], bf, acc[mt][nt], 0, 0, 0);
        }
        if (step + 2 < 32) {         // prefetch step+2 into the buffer just consumed
            const int sn = (step + 2) >> 3, dcn = (step + 2) & 7;
#pragma unroll
            for (int nt = 0; nt < 4; ++nt)
                bbuf[cur][nt] = *(const int4*)(ebf + ((kq + sn * 64 + nt * 16 + n16) << 8) + dcn * 32 + q * 8);
        }
        if (dc == 7) {               // subtile epilogue, register-only thresholds
            float e2hr[4]; int kg[4];
#pragma unroll
            for (int nt = 0; nt < 4; ++nt) {
                kg[nt] = kq + s * 64 + nt * 16 + n16;
                e2hr[nt] = e2hw[kg[nt]];
            }
#pragma unroll
            for (int mt = 0; mt < 4; ++mt)
#pragma unroll
                for (int nt = 0; nt < 4; ++nt)
#pragma unroll
                    for (int r = 0; r < 4; ++r)
                        acc[mt][nt][r] -= e2hr[nt];    // s~ = dot - e2/2
#pragma unroll
            for (int mt = 0; mt < 4; ++mt)
#pragma unroll
                for (int r = 0; r < 4; ++r) {
                    float m = fmaxf(fmaxf(acc[mt][0][r], acc[mt][1][r]),
                                    fmaxf(acc[mt][2][r], acc[mt][3][r]));
                    m = fmaxf(m, __shfl_xor(m, 1, 64));
                    m = fmaxf(m, __shfl_xor(m, 2, 64));
                    m = fmaxf(m, __shfl_xor(m, 4, 64));
                    m = fmaxf(m, __shfl_xor(m, 8, 64));
                    Mx[mt][r] = fmaxf(Mx[mt][r], m);   // max updated BEFORE record: no redo
                }
#pragma unroll
            for (int mt = 0; mt < 4; ++mt)
#pragma unroll
                for (int r = 0; r < 4; ++r) {
                    const int row = mt * 16 + q * 4 + r;
                    const float th = Mx[mt][r] - epsS[row];
#pragma unroll
                    for (int nt = 0; nt < 4; ++nt) {
                        if (acc[mt][nt][r] >= th) {
                            unsigned int p = atomicAdd(&cntS[row], 1u);
                            if (p < CL) clS[row * CL + p] = kg[nt];
                            else ovfS = 1;
                        }
                    }
                }
#pragma unroll
            for (int mt = 0; mt < 4; ++mt)
#pragma unroll
                for (int nt = 0; nt < 4; ++nt) acc[mt][nt] = (f32x4)0.0f;
        }
    }
    __syncthreads();

    // -------- phase 2: exact recheck, flat queue (bit-identical fp32 chain) --------
    if (tid == 0) {
        int run = 0;
#pragma unroll 1
        for (int p = 0; p < 64; ++p) {
            offS[p] = run;
            unsigned int c = cntS[p]; if (c > CL) c = CL;
            run += (int)c;
        }
        offS[64] = run;
    }
    __syncthreads();
    const int T = offS[64];
#pragma unroll 1
    for (int base = 0; base < T; base += 256) {
        const int g = base + tid;
        const bool active = g < T;
        int ppt = 0, kk = 0;
        if (active) {
            int lo = 0, hi = 64;
            while (hi - lo > 1) { int mid = (lo + hi) >> 1; if (offS[mid] <= g) lo = mid; else hi = mid; }
            ppt = lo;
            kk = clS[ppt * CL + (g - offS[ppt])];
        }
        float a = 0.0f;
#pragma unroll 1
        for (int dc = 0; dc < 8; ++dc) {
            __syncthreads();
            {
                const float* zc = z + zb + (((dc << 5) + dd0) << 10) + 4 * qq;
                float4 v0 = *(const float4*)zc;
                float4 v1 = *(const float4*)(zc + (16 << 10));
                *(float4*)(zx + dd0 * 68 + 4 * qq) = v0;
                *(float4*)(zx + (dd0 + 16) * 68 + 4 * qq) = v1;
            }
            __syncthreads();
            if (active) {
                const float* er = emb + (kk << 8) + (dc << 5);
                float ev[32];
#pragma unroll
                for (int c = 0; c < 8; ++c) *(float4*)(ev + 4 * c) = *(const float4*)(er + 4 * c);
#pragma unroll
                for (int dd = 0; dd < 32; ++dd)
                    a = __builtin_fmaf(zx[dd * 68 + ppt], ev[dd], a);
            }
        }
        if (active) {
            float t1 = __fadd_rn(z2S[ppt], e2w[kk]);
            float d  = __fsub_rn(t1, __fmul_rn(2.0f, a));
            atomicMin(&bestS[ppt], pack_vi(d, kk));    // lexicographic (d,k) = np argmin
        }
    }
    __syncthreads();

    if (ovfS) {   // near-impossible fallback: full exact scan for overflowed points
#pragma unroll 1
        for (int row = 0; row < 64; ++row) {
            if (cntS[row] <= (unsigned)CL) continue;
            float fa[4] = {0.f, 0.f, 0.f, 0.f};
            for (int dt = 0; dt < 8; ++dt) {
                __syncthreads();
                {
                    const float* zc = z + zb + (((dt << 5) + dd0) << 10) + 4 * qq;
                    float4 v0 = *(const float4*)zc;
                    float4 v1 = *(const float4*)(zc + (16 << 10));
                    *(float4*)(zx + dd0 * 68 + 4 * qq) = v0;
                    *(float4*)(zx + (dd0 + 16) * 68 + 4 * qq) = v1;
                }
                __syncthreads();
                for (int c = 0; c < 4; ++c) {
                    const float* er = emb + ((tid + 256 * c) << 8) + (dt << 5);
                    for (int dd = 0; dd < 32; ++dd)
                        fa[c] = __builtin_fmaf(zx[dd * 68 + row], er[dd], fa[c]);
                }
            }
            for (int c = 0; c < 4; ++c) {
                int k = tid + 256 * c;
                float t1 = __fadd_rn(z2S[row], e2w[k]);
                float d  = __fsub_rn(t1, __fmul_rn(2.0f, fa[c]));
                atomicMin(&bestS[row], pack_vi(d, k));
            }
            __syncthreads();
        }
    }
    __syncthreads();
    if (tid < 64) {
        int kb = (int)(unsigned int)(bestS[tid] & 0xFFFFFFFFULL);
        kbS[tid] = kb;
        out_idx[n0 + tid] = (float)kb;
    }
    __syncthreads();

    // -------- phase 3: zq + loss via LDS transpose (coalesced writes) --------
    double sl = 0.0;
    const int row3 = tid & 63, part3 = tid >> 6;
#pragma unroll 1
    for (int dc = 0; dc < 8; ++dc) {
        {
            const float* er = emb + (kbS[row3] << 8) + (dc << 5) + part3 * 8;
            float4 e0 = *(const float4*)er;
            float4 e1 = *(const float4*)(er + 4);
            zx[(part3 * 8 + 0) * 68 + row3] = e0.x;
            zx[(part3 * 8 + 1) * 68 + row3] = e0.y;
            zx[(part3 * 8 + 2) * 68 + row3] = e0.z;
            zx[(part3 * 8 + 3) * 68 + row3] = e0.w;
            zx[(part3 * 8 + 4) * 68 + row3] = e1.x;
            zx[(part3 * 8 + 5) * 68 + row3] = e1.y;
            zx[(part3 * 8 + 6) * 68 + row3] = e1.z;
            zx[(part3 * 8 + 7) * 68 + row3] = e1.w;
        }
        __syncthreads();
#pragma unroll
        for (int h = 0; h < 2; ++h) {
            const int dd = dd0 + 16 * h;
            float4 ev = *(const float4*)(zx + dd * 68 + 4 * qq);
            const float* zp = z + zb + (((dc << 5) + dd) << 10) + 4 * qq;
            float4 zv = *(const float4*)zp;
            *(float4*)(zq + zb + (((dc << 5) + dd) << 10) + 4 * qq) = ev;
            float d0 = ev.x - zv.x, d1 = ev.y - zv.y, d2 = ev.z - zv.z, d3 = ev.w - zv.w;
            sl = fma((double)d0, (double)d0, sl);
            sl = fma((double)d1, (double)d1, sl);
            sl = fma((double)d2, (double)d2, sl);
            sl = fma((double)d3, (double)d3, sl);
        }
        __syncthreads();
    }
    for (int off = 32; off; off >>= 1) sl += __shfl_down(sl, off, 64);
    if (l == 0) sredL[w] = sl;
    __syncthreads();
    if (tid == 0) {
        double t = (sredL[0] + sredL[1]) + (sredL[2] + sredL[3]);
        atomicAdd(loss_acc, t);
        __threadfence();
        unsigned int old = atomicAdd(ticket, 1u);
        if (old == gridDim.x - 1) {
            double total = atomicAdd(loss_acc, 0.0);   // coherent read
            out_loss[0] = (float)(1.25 * (total / 8388608.0));
        }
    }
}

extern "C" void kernel_launch(void* const* d_in, const int* in_sizes, int n_in,
                              void* d_out, int out_size, void* d_ws, size_t ws_size,
                              hipStream_t stream) {
    const float* z   = (const float*)d_in[0];
    const float* emb = (const float*)d_in[1];
    float* out = (float*)d_out;

    // ws: e2[1024] @0 | e2h[1024] @4096 | ebf16[262144]u16 @8192 | loss f64 @532480 | ticket @532488
    float* e2w = (float*)d_ws;
    float* e2hw = (float*)((char*)d_ws + 4096);
    unsigned short* ebf = (unsigned short*)((char*)d_ws + 8192);
    double* loss_acc = (double*)((char*)d_ws + 532480);
    unsigned int* ticket = (unsigned int*)((char*)d_ws + 532488);

    setup_e_kernel<<<4, 256, 0, stream>>>(emb, e2w, e2hw, ebf, loss_acc, ticket);
    vq_kernel<<<NPTS / 64, 256, 0, stream>>>(z, emb, ebf, e2w, e2hw,
                                             out + IDX_OFF, out + ZQ_OFF,
                                             loss_acc, ticket, out + LOSS_OFF);
}